// Round 8
// baseline (5126.777 us; speedup 1.0000x reference)
//
#include <hip/hip_runtime.h>
#include <stdint.h>

#define TT 128
#define BB 128
#define NN 1024

// World model (verified bit-exact in R9):
//   tx: packed bf16 storage (runtime-probed each launch; probe also handles f32),
//   W : f32 storage, bf16-rounded values; b: f32; out: f32.
//   Reference recurrent sum: OpenBLAS sgemm kc=384 panels, sequential-k
//   single accumulator per panel, a = (P0 + P1) + P2.  With binary y all
//   products are exact, so this association is reproduced exactly.
//
// R17 == R16 resubmitted (previous round died to a container/broker infra
// failure; audit found no hang path — co-residency guaranteed at 66KB LDS,
// block-uniform barrier counts, safe vmcnt semantics).
//
// R16 theory: R13/R14/R15 (three different gather structures) all measured
// 31.4k cy/step -> the wall is per-CU memory-pipe INSTRUCTION slots: all
// three deliver 1 value/lane/instr (2640 consume instrs/CU/step). R16
// delivers TWO values/lane/instr: each thread owns two ADJACENT columns
// (n=2i,2i+1), consume = 1 ds_read_b32/row/thread (1320 DS instrs),
// unpack = 2 VALU (w<<16, w&0xFFFF0000 are the two f32 bit patterns).
//   - 256 threads/block (4 waves), grid 256 (half-sample split as R13)
//   - R15-style linear gload_lds16 staging, 32-row chunks, dbuf,
//     counted vmcnt(8), ~12 barrier-pairs/step (vs R15's 42)
//   - ballot repack: 2 ballots/wave Morton-interleaved into the SAME
//     mask-chunk wire format as R13 (exchange protocol byte-identical)
//   - LDS 66KB -> capacity 2 blocks/CU -> co-residency (spin) guaranteed
//   - association untouched: per-column ascending-k chains, one acc per
//     panel, (P0+P1)+P2, trailing sentinels k=1024 -> zero row (+0.0f).

typedef unsigned short ushort8 __attribute__((ext_vector_type(8)));

__device__ __forceinline__ float bfbits2f(uint32_t lo16) {
  union { uint32_t i; float f; } c;
  c.i = lo16 << 16;
  return c.f;
}

__device__ __forceinline__ float bits2f(uint32_t b) {
  union { uint32_t i; float f; } c;
  c.i = b;
  return c.f;
}

__device__ __forceinline__ void gload_lds16(const void* g, void* l) {
  __builtin_amdgcn_global_load_lds(
      (const __attribute__((address_space(1))) uint32_t*)g,
      (__attribute__((address_space(3))) uint32_t*)l, 16, 0, 0);
}

// ---------------------------------------------------------------------------
// Kernel 0: in-place f32 transpose of W (tile-pair swap)  +  bf16 repack of
// W^T into ws  +  losslessness check (dirty flag set if any f32 word has
// nonzero low 16 bits — then the gather kernels use the f32 path).
// ---------------------------------------------------------------------------
__global__ __launch_bounds__(256) void w_transpose_repack(
    float* __restrict__ W, uint16_t* __restrict__ WtBf,
    uint32_t* __restrict__ dirty) {
  __shared__ float ta[32][33];
  __shared__ float tb[32][33];

  int rem = blockIdx.x;
  int I = 0;
  while (rem >= (32 - I)) { rem -= (32 - I); ++I; }
  const int J = I + rem;

  const int lx = threadIdx.x & 31;
  const int ly = threadIdx.x >> 5;  // 0..7
  uint32_t bad = 0;

  if (I == J) {
#pragma unroll
    for (int i = 0; i < 4; ++i)
      ta[ly + i * 8][lx] = W[(I * 32 + ly + i * 8) * NN + J * 32 + lx];
    __syncthreads();
#pragma unroll
    for (int i = 0; i < 4; ++i) {
      const int idx = (I * 32 + ly + i * 8) * NN + J * 32 + lx;
      const float v = ta[lx][ly + i * 8];
      const uint32_t bits = __float_as_uint(v);
      W[idx] = v;
      WtBf[idx] = (uint16_t)(bits >> 16);
      bad |= (bits & 0xFFFFu);
    }
  } else {
#pragma unroll
    for (int i = 0; i < 4; ++i) {
      ta[ly + i * 8][lx] = W[(I * 32 + ly + i * 8) * NN + J * 32 + lx];
      tb[ly + i * 8][lx] = W[(J * 32 + ly + i * 8) * NN + I * 32 + lx];
    }
    __syncthreads();
#pragma unroll
    for (int i = 0; i < 4; ++i) {
      const int idxA = (J * 32 + ly + i * 8) * NN + I * 32 + lx;
      const float va = ta[lx][ly + i * 8];
      const uint32_t bitsA = __float_as_uint(va);
      W[idxA] = va;
      WtBf[idxA] = (uint16_t)(bitsA >> 16);
      bad |= (bitsA & 0xFFFFu);

      const int idxB = (I * 32 + ly + i * 8) * NN + J * 32 + lx;
      const float vb = tb[lx][ly + i * 8];
      const uint32_t bitsB = __float_as_uint(vb);
      W[idxB] = vb;
      WtBf[idxB] = (uint16_t)(bitsB >> 16);
      bad |= (bitsB & 0xFFFFu);
    }
  }
  const unsigned long long bm = __ballot(bad != 0);
  if ((threadIdx.x & 63) == 0 && bm) atomicOr(dirty, 1u);
}

// ---------------------------------------------------------------------------
// Kernel 1a (primary): per-HALF-sample LIF, 2 cols/thread. 256 blocks x 256
// threads; block bb: sample b = bb&127, half h = bb>>7, partner bb^128.
// ---------------------------------------------------------------------------
__global__ __launch_bounds__(256) void lif_half(
    const void* __restrict__ tx_raw, const float* __restrict__ bias,
    const float* __restrict__ WtF32, const uint16_t* __restrict__ WtBf,
    const uint32_t* __restrict__ dirty,
    unsigned long long* __restrict__ gmask, float* __restrict__ out) {
  const int bb = blockIdx.x;
  const int b = bb & 127;          // sample
  const int h = bb >> 7;           // neuron half
  const int pp = bb ^ 128;         // partner block (other half)
  const int tid = threadIdx.x;     // 0..255
  const int lane = tid & 63;
  const int wv = tid >> 6;         // 0..3
  const int n0 = (h << 9) + tid * 2;  // thread owns global cols n0, n0+1

  __shared__ uint16_t sbuf[2][32][512] __attribute__((aligned(16)));  // 64KB
  __shared__ uint16_t lst[NN] __attribute__((aligned(16)));
  __shared__ unsigned long long smask[16];  // chunk j covers k in [j*64,(j+1)*64)
  __shared__ int sprobe;

  // ---- runtime tx-storage probe (bf16-packed vs f32), as verified in R9 ----
  if (tid == 0) sprobe = 0;
  __syncthreads();
  {
    const uint32_t* txw = (const uint32_t*)tx_raw;
    int local = 0;
#pragma unroll
    for (int i = 0; i < 4; ++i) {
      const uint32_t f = (txw[tid * 4 + i] >> 7) & 0xFFu;
      local += (f >= 0x74u && f < 0x81u) ? 1 : 0;
    }
    atomicAdd(&sprobe, local);
  }
  __syncthreads();
  const bool tx_is_bf16 = (sprobe > 512);    // of 1024 sampled words
  const bool w_bf = (*dirty == 0u);          // bf16 repack lossless?

  const uint16_t* __restrict__ txh = (const uint16_t*)tx_raw;
  const float* __restrict__ txf = (const float*)tx_raw;
  const float2 bz2 = *(const float2*)(bias + n0);

  const char* __restrict__ wbase = (const char*)WtBf;
  const size_t lane16 = (size_t)(lane << 4);
  const size_t hoff = (size_t)(h << 10);     // byte offset of this half's cols

  float v0 = 0.0f, v1 = 0.0f;  // membranes (REST = 0)
  int y0 = 0, y1 = 0;          // previous spikes

  // Morton spread: bit q of x -> bit 2q of result.
  auto spread = [](uint32_t x) -> unsigned long long {
    unsigned long long z = x;
    z = (z | (z << 16)) & 0x0000FFFF0000FFFFull;
    z = (z | (z << 8))  & 0x00FF00FF00FF00FFull;
    z = (z | (z << 4))  & 0x0F0F0F0F0F0F0F0Full;
    z = (z | (z << 2))  & 0x3333333333333333ull;
    z = (z | (z << 1))  & 0x5555555555555555ull;
    return z;
  };

  for (int t = 0; t < TT; ++t) {
    const int sl = t & 3;  // mod-4 slot
    // ---- ballots + repack to mask-chunk wire format (2 chunks per wave) ----
    const unsigned long long b0 = __ballot(y0);
    const unsigned long long b1 = __ballot(y1);
    // wave wv covers cols [h*512 + wv*128, +128) = mask chunks h*8+2wv, +1.
    // chunk bit 2q   = y0 of lane q  (col base+2q)
    // chunk bit 2q+1 = y1 of lane q  (col base+2q+1)
    const unsigned long long m0 =
        spread((uint32_t)b0) | (spread((uint32_t)b1) << 1);
    const unsigned long long m1 =
        spread((uint32_t)(b0 >> 32)) | (spread((uint32_t)(b1 >> 32)) << 1);
    if (lane == 0) {
      smask[h * 8 + 2 * wv] = m0;
      smask[h * 8 + 2 * wv + 1] = m1;
    }
    if (lane < 4) {
      // cell index = chunkLocal*2 + word = wv*4 + lane (same format as R13)
      const unsigned long long msel = (lane & 2) ? m1 : m0;
      const uint32_t word = (lane & 1) ? (uint32_t)(msel >> 32) : (uint32_t)msel;
      const unsigned long long cell =
          ((unsigned long long)(t + 1) << 32) | (unsigned long long)word;
      __hip_atomic_store(&gmask[((size_t)bb * 4 + sl) * 16 + wv * 4 + lane],
                         cell, __ATOMIC_RELAXED, __HIP_MEMORY_SCOPE_AGENT);
    }

    // issue tx load early; consumed after the gather
    const int off = (t * BB + b) * NN + n0;
    float x0, x1;
    if (tx_is_bf16) {
      const uint32_t w =
          __builtin_nontemporal_load((const uint32_t*)&txh[off]);
      x0 = bits2f(w << 16);
      x1 = bits2f(w & 0xFFFF0000u);
    } else {
      const uint64_t w2 =
          __builtin_nontemporal_load((const uint64_t*)&txf[off]);
      x0 = bits2f((uint32_t)w2);
      x1 = bits2f((uint32_t)(w2 >> 32));
    }

    __syncthreads();  // SYNC_A: own smask half visible; prior step fully done
    if (tid < 16) {
      // spin on partner's tagged cell; tag==t+1 guarantees payload is the
      // step-t word (single-cell atomicity; no fences required)
      const size_t ci = ((size_t)pp * 4 + sl) * 16 + tid;
      unsigned long long cell;
      while (((cell = __hip_atomic_load(&gmask[ci], __ATOMIC_RELAXED,
                                        __HIP_MEMORY_SCOPE_AGENT)) >>
              32) != (unsigned long long)(t + 1)) {
        __builtin_amdgcn_s_sleep(1);
      }
      ((uint32_t*)smask)[(1 - h) * 16 + tid] = (uint32_t)cell;
    }
    __syncthreads();  // SYNC_B: all 16 mask chunks in LDS

    // ---- per-thread counts/prefixes from the 16 mask chunks ----
    unsigned long long mk[16];
    int cnt[16];
#pragma unroll
    for (int i = 0; i < 16; ++i) {
      mk[i] = smask[i];
      cnt[i] = __popcll(mk[i]);
    }
    int pref[16];
    {
      int s = 0;
#pragma unroll
      for (int j = 0; j < 6; ++j) { pref[j] = s; s += cnt[j]; }
    }
    {
      int s = 384;
#pragma unroll
      for (int j = 6; j < 12; ++j) { pref[j] = s; s += cnt[j]; }
    }
    {
      int s = 768;
#pragma unroll
      for (int j = 12; j < 16; ++j) { pref[j] = s; s += cnt[j]; }
    }
    const int c0 = pref[5] + cnt[5];          // panel 0 count (k < 384)
    const int c1 = pref[11] + cnt[11] - 384;  // panel 1 count
    const int c2 = pref[15] + cnt[15] - 768;  // panel 2 count

    // ---- build full active list: wave wv materializes chunks 4wv..4wv+3 ----
#pragma unroll
    for (int jj = 0; jj < 4; ++jj) {
      const int j = wv * 4 + jj;
      const unsigned long long bits = mk[j];
      if ((bits >> lane) & 1ull) {
        const int below = __builtin_amdgcn_mbcnt_hi(
            (uint32_t)(bits >> 32),
            __builtin_amdgcn_mbcnt_lo((uint32_t)bits, 0));
        lst[pref[j] + below] = (uint16_t)(j * 64 + lane);
      }
    }
    // sentinel padding to x32 per panel (k=NN -> zeroed row, +0.0f exact)
    if (tid < 96) {
      const int p = tid >> 5, jn = tid & 31;
      const int c = (p == 0) ? c0 : ((p == 1) ? c1 : c2);
      if (c + jn < ((c + 31) & ~31)) lst[p * 384 + c + jn] = (uint16_t)NN;
    }
    __syncthreads();  // SYNC_C: lst complete

    // ---- recurrent term: (P0 + P1) + P2, sequential k within panels ----
    float P0a = 0.0f, P0b = 0.0f, P1a = 0.0f, P1b = 0.0f,
          P2a = 0.0f, P2b = 0.0f;
    if (w_bf) {
      const int n0c = (c0 + 31) >> 5;
      const int n1c = (c1 + 31) >> 5;
      const int n2c = (c2 + 31) >> 5;
      const int nct = n0c + n1c + n2c;

      // stage 32-row chunk c into buffer cb: wave wv stages its 8 rows.
      auto stage = [&](int c, int cb) {
        int rb;
        if (c < n0c) rb = c * 32;
        else if (c < n0c + n1c) rb = 384 + (c - n0c) * 32;
        else rb = 768 + (c - n0c - n1c) * 32;
        const ushort8 kv = *(const ushort8*)(lst + rb + wv * 8);
#pragma unroll
        for (int j = 0; j < 8; ++j) {
          const int k = __builtin_amdgcn_readfirstlane((int)kv[j]);
          gload_lds16(wbase + ((size_t)k << 11) + hoff + lane16,
                      &sbuf[cb][wv * 8 + j][0]);
        }
      };
      // ordered consume of one staged chunk: 32 rows ascending k; both cols.
      auto consume32 = [&](int cb, float& A, float& B) {
        const uint32_t* rp = (const uint32_t*)(&sbuf[cb][0][0]) + tid;
#pragma unroll
        for (int r = 0; r < 32; ++r) {
          const uint32_t w = rp[r * 256];
          A += bits2f(w << 16);
          B += bits2f(w & 0xFFFF0000u);
        }
      };

      if (nct > 0) {
        stage(0, 0);
        if (nct > 1) stage(1, 1);
        for (int c = 0; c < nct; ++c) {
          const int cb = c & 1;
          // counted wait: chunk c's 8 loads done (next chunk's stay in
          // flight), then barrier so all waves see the buffer complete
          if (c + 1 < nct)
            asm volatile("s_waitcnt vmcnt(8)\n\ts_barrier" ::: "memory");
          else
            asm volatile("s_waitcnt vmcnt(0)\n\ts_barrier" ::: "memory");

          if (c < n0c) consume32(cb, P0a, P0b);
          else if (c < n0c + n1c) consume32(cb, P1a, P1b);
          else consume32(cb, P2a, P2b);

          // all waves done reading cb before anyone restages it
          asm volatile("s_barrier" ::: "memory");
          if (c + 2 < nct) stage(c + 2, cb);
        }
      }
    } else {
      // f32 fallback (cold path): unpadded bounds, dual-col 8B loads.
      auto gF2 = [&](int s, int e, float& A, float& B) {
        for (int i = s; i < e; ++i) {
          const int k = __builtin_amdgcn_readfirstlane((int)lst[i]);
          const float2 w = *(const float2*)(WtF32 + ((size_t)k << 10) + n0);
          A += w.x;
          B += w.y;
        }
      };
      gF2(0, c0, P0a, P0b);
      gF2(384, 384 + c1, P1a, P1b);
      gF2(768, 768 + c2, P2a, P2b);
    }
    const float a0 = (P0a + P1a) + P2a;
    const float a1 = (P0b + P1b) + P2b;

    // ---- LIF update, reference op order, f32, both cols ----
    const float xv0 = (x0 + a0) + bz2.x;
    const float xv1 = (x1 + a1) + bz2.y;
    v0 = (y0 ? 0.0f : 0.5f * v0) + xv0;
    v1 = (y1 ? 0.0f : 0.5f * v1) + xv1;
    y0 = (v0 > 0.5f);
    y1 = (v1 > 0.5f);

    const uint32_t f0 = y0 ? 0x3F800000u : 0u;
    const uint32_t f1 = y1 ? 0x3F800000u : 0u;
    __builtin_nontemporal_store(((uint64_t)f1 << 32) | (uint64_t)f0,
                                (uint64_t*)&out[off]);
    // No end-of-step barrier needed: smask/lst(t+1) writes happen after
    // SYNC_A/B(t+1); all LDS reads of step t complete before those.
  }
}

// ---------------------------------------------------------------------------
// Kernel 1b (fallback, R10-verified): per-sample LIF, 128 blocks x 1024 thr.
// Used only if ws_size cannot hold the mask exchange buffers.
// ---------------------------------------------------------------------------
__global__ __launch_bounds__(1024) void lif_persample(
    const void* __restrict__ tx_raw, const float* __restrict__ bias,
    const float* __restrict__ WtF32, const uint16_t* __restrict__ WtBf,
    const uint32_t* __restrict__ dirty, float* __restrict__ out) {
  const int b = blockIdx.x;
  const int tid = threadIdx.x;
  const int lane = tid & 63;
  const int wv = tid >> 6;

  __shared__ uint16_t lst[NN] __attribute__((aligned(16)));
  __shared__ int wcnt[16];
  __shared__ int sprobe;

  if (tid == 0) sprobe = 0;
  __syncthreads();
  {
    const uint32_t* txw = (const uint32_t*)tx_raw;
    int local = 0;
#pragma unroll
    for (int i = 0; i < 2; ++i) {
      const uint32_t f = (txw[tid * 2 + i] >> 7) & 0xFFu;
      local += (f >= 0x74u && f < 0x81u) ? 1 : 0;
    }
    atomicAdd(&sprobe, local);
  }
  __syncthreads();
  const bool tx_is_bf16 = (sprobe > 1024);
  const bool w_bf = (*dirty == 0u);

  const uint16_t* __restrict__ txh = (const uint16_t*)tx_raw;
  const float* __restrict__ txf = (const float*)tx_raw;
  const float bz = bias[tid];

  const int pidx = (wv < 6) ? 0 : ((wv < 12) ? 1 : 2);
  const int pw0 = (pidx == 0) ? 0 : ((pidx == 1) ? 6 : 12);

  const uint16_t* __restrict__ rowB = WtBf + tid;
  const float* __restrict__ rowF = WtF32 + tid;

  float v = 0.0f;
  int y = 0;

  auto gB = [&](int pbase, int cnt) -> float {
    float acc = 0.0f;
    for (int i = 0; i < cnt; i += 32) {
      const ushort8* lp = (const ushort8*)(lst + pbase + i);
      const ushort8 a0 = lp[0];
      const ushort8 a1 = lp[1];
      const ushort8 a2 = lp[2];
      const ushort8 a3 = lp[3];
      float wbuf[32];
#pragma unroll
      for (int u = 0; u < 8; ++u) {
        const int k = __builtin_amdgcn_readfirstlane((int)a0[u]);
        wbuf[u] = bfbits2f((uint32_t)rowB[k << 10]);
      }
#pragma unroll
      for (int u = 0; u < 8; ++u) {
        const int k = __builtin_amdgcn_readfirstlane((int)a1[u]);
        wbuf[8 + u] = bfbits2f((uint32_t)rowB[k << 10]);
      }
#pragma unroll
      for (int u = 0; u < 8; ++u) {
        const int k = __builtin_amdgcn_readfirstlane((int)a2[u]);
        wbuf[16 + u] = bfbits2f((uint32_t)rowB[k << 10]);
      }
#pragma unroll
      for (int u = 0; u < 8; ++u) {
        const int k = __builtin_amdgcn_readfirstlane((int)a3[u]);
        wbuf[24 + u] = bfbits2f((uint32_t)rowB[k << 10]);
      }
#pragma unroll
      for (int u = 0; u < 32; ++u) acc += wbuf[u];
    }
    return acc;
  };

  auto gF = [&](int s, int e) -> float {
    float acc = 0.0f;
    int i = s;
    for (; i + 8 <= e; i += 8) {
      float w[8];
#pragma unroll
      for (int u = 0; u < 8; ++u) {
        const int k = __builtin_amdgcn_readfirstlane((int)lst[i + u]);
        w[u] = rowF[k << 10];
      }
#pragma unroll
      for (int u = 0; u < 8; ++u) acc += w[u];
    }
    for (; i < e; ++i) {
      const int k = __builtin_amdgcn_readfirstlane((int)lst[i]);
      acc += rowF[k << 10];
    }
    return acc;
  };

  for (int t = 0; t < TT; ++t) {
    const unsigned long long m = __ballot(y);
    if (lane == 0) wcnt[wv] = __popcll(m);
    __syncthreads();
    int base = 0, c0 = 0, c1 = 0, c2 = 0;
#pragma unroll
    for (int w = 0; w < 16; ++w) {
      const int c = wcnt[w];
      c0 += (w < 6) ? c : 0;
      c1 += (w >= 6 && w < 12) ? c : 0;
      c2 += (w >= 12) ? c : 0;
      base += (w >= pw0 && w < wv) ? c : 0;
    }
    if (y) {
      const int below = __builtin_amdgcn_mbcnt_hi(
          (uint32_t)(m >> 32), __builtin_amdgcn_mbcnt_lo((uint32_t)m, 0));
      lst[pidx * 384 + base + below] = (uint16_t)tid;
    }
    if (tid < 96) {
      const int p = tid >> 5, jn = tid & 31;
      const int c = (p == 0) ? c0 : ((p == 1) ? c1 : c2);
      if (c + jn < ((c + 31) & ~31)) lst[p * 384 + c + jn] = (uint16_t)NN;
    }
    __syncthreads();

    float P0, P1, P2;
    if (w_bf) {
      P0 = gB(0, (c0 + 31) & ~31);
      P1 = gB(384, (c1 + 31) & ~31);
      P2 = gB(768, (c2 + 31) & ~31);
    } else {
      P0 = gF(0, c0);
      P1 = gF(384, 384 + c1);
      P2 = gF(768, 768 + c2);
    }
    const float a = (P0 + P1) + P2;

    const int off = (t * BB + b) * NN + tid;
    const float xx = tx_is_bf16
        ? bfbits2f((uint32_t)__builtin_nontemporal_load(&txh[off]))
        : __builtin_nontemporal_load(&txf[off]);
    const float xv = (xx + a) + bz;
    v = (y ? 0.0f : 0.5f * v) + xv;
    y = (v > 0.5f);

    __builtin_nontemporal_store(y ? 1.0f : 0.0f, &out[off]);
  }
}

extern "C" void kernel_launch(void* const* d_in, const int* in_sizes, int n_in,
                              void* d_out, int out_size, void* d_ws, size_t ws_size,
                              hipStream_t stream) {
  // Inputs by element count: tx = 128*128*1024 (bf16-packed),
  // W = 1024*1024 (f32, bf16-valued), b = 1024 (f32).
  const void* tx = nullptr;
  float* W = nullptr;
  const float* bs = nullptr;
  for (int i = 0; i < n_in; ++i) {
    if (in_sizes[i] == TT * BB * NN) tx = d_in[i];
    else if (in_sizes[i] == NN * NN) W = (float*)d_in[i];
    else if (in_sizes[i] == NN) bs = (const float*)d_in[i];
  }
  float* out = (float*)d_out;                     // [T, B, N] f32 spikes

  // Workspace layout:
  //   [0, 2MB)                bf16 W^T (1024 rows)
  //   [2MB, 2MB+2KB)          zero row (sentinel k=1024)
  //   @2MB+2048               dirty flag (u32)
  //   @2MB+4096               gmask: u64[256 blocks][4 slots][16 cells] = 128KB
  const size_t MB2 = 2u * 1024u * 1024u;
  uint16_t* WtBf = (uint16_t*)d_ws;
  uint16_t* zrow = WtBf + NN * NN;                // row index 1024
  uint32_t* dirty = (uint32_t*)((char*)d_ws + MB2 + 2048u);
  unsigned long long* gmask =
      (unsigned long long*)((char*)d_ws + MB2 + 4096u);
  const size_t GMASK_BYTES = 256u * 4u * 16u * 8u;  // 131072
  const size_t need = MB2 + 4096u + GMASK_BYTES;

  // ws is poisoned 0xAA each launch — clear dirty flag, sentinel row, cells.
  hipMemsetAsync(dirty, 0, sizeof(uint32_t), stream);
  hipMemsetAsync(zrow, 0, NN * sizeof(uint16_t), stream);

  w_transpose_repack<<<dim3(528), dim3(256), 0, stream>>>(W, WtBf, dirty);

  if (ws_size >= need) {
    hipMemsetAsync(gmask, 0, GMASK_BYTES, stream);
    lif_half<<<dim3(256), dim3(256), 0, stream>>>(tx, bs, W, WtBf, dirty,
                                                  gmask, out);
  } else {
    lif_persample<<<dim3(BB), dim3(1024), 0, stream>>>(tx, bs, W, WtBf, dirty,
                                                       out);
  }
}

// Round 9
// 1750.459 us; speedup vs baseline: 2.9288x; 2.9288x over previous
//
#include <hip/hip_runtime.h>
#include <stdint.h>

#define TT 128
#define BB 128
#define NN 1024

// World model (verified bit-exact in R9):
//   tx: packed bf16 storage (runtime-probed each launch; probe also handles f32),
//   W : f32 storage, bf16-rounded values; b: f32; out: f32.
//   Reference recurrent sum: OpenBLAS sgemm kc=384 panels, sequential-k
//   single accumulator per panel, a = (P0 + P1) + P2.  With binary y all
//   products are exact, so this association is reproduced exactly.
//
// R18: revert to the R13 scaffold (512-thr split blocks, 8 waves/CU,
// fenceless tagged-cell exchange — verified twice) and replace ONLY the
// per-wave gather. R16's 4-wave chunk-synchronous design regressed 3x
// (barrier+vmcnt stalls with nothing else resident); consume-instruction
// count was falsified (R10 5280 vs R13 2640 instrs -> only 10% delta).
// The never-yet-reduced quantity is VMEM instrs per wave (330 in ALL
// variants). New gather:
//   - ONE gload_lds16 stages 8 rows: lane j sources row lst[pb+(j>>3)],
//     bytes (j&7)*16 of this wave's 128B row-slice; linear LDS dest
//     (lane*16) lands row-major [8][128B]. 330 -> 42 VMEM instrs/wave.
//   - wave-PRIVATE double buffer (2x1KB/wave) -> zero barriers in gather;
//     per-wave vmcnt(1/0); explicit lgkmcnt(0) before re-staging a
//     consumed buffer (ds_reads must land before gload overwrites).
//   - consume: 8x ds_read_u16 at buf[r*64+lane] (2-way alias = free),
//     adds strictly sequential ascending-k, one acc per panel -> exact.
//   - panels sentinel-padded to x8 (k=1024 -> zero row, +0.0f exact).

typedef unsigned short ushort8 __attribute__((ext_vector_type(8)));

__device__ __forceinline__ float bfbits2f(uint32_t lo16) {
  union { uint32_t i; float f; } c;
  c.i = lo16 << 16;
  return c.f;
}

__device__ __forceinline__ void gload_lds16(const void* g, void* l) {
  __builtin_amdgcn_global_load_lds(
      (const __attribute__((address_space(1))) uint32_t*)g,
      (__attribute__((address_space(3))) uint32_t*)l, 16, 0, 0);
}

// ---------------------------------------------------------------------------
// Kernel 0: in-place f32 transpose of W (tile-pair swap)  +  bf16 repack of
// W^T into ws  +  losslessness check (dirty flag set if any f32 word has
// nonzero low 16 bits — then the gather kernels use the f32 path).
// ---------------------------------------------------------------------------
__global__ __launch_bounds__(256) void w_transpose_repack(
    float* __restrict__ W, uint16_t* __restrict__ WtBf,
    uint32_t* __restrict__ dirty) {
  __shared__ float ta[32][33];
  __shared__ float tb[32][33];

  int rem = blockIdx.x;
  int I = 0;
  while (rem >= (32 - I)) { rem -= (32 - I); ++I; }
  const int J = I + rem;

  const int lx = threadIdx.x & 31;
  const int ly = threadIdx.x >> 5;  // 0..7
  uint32_t bad = 0;

  if (I == J) {
#pragma unroll
    for (int i = 0; i < 4; ++i)
      ta[ly + i * 8][lx] = W[(I * 32 + ly + i * 8) * NN + J * 32 + lx];
    __syncthreads();
#pragma unroll
    for (int i = 0; i < 4; ++i) {
      const int idx = (I * 32 + ly + i * 8) * NN + J * 32 + lx;
      const float v = ta[lx][ly + i * 8];
      const uint32_t bits = __float_as_uint(v);
      W[idx] = v;
      WtBf[idx] = (uint16_t)(bits >> 16);
      bad |= (bits & 0xFFFFu);
    }
  } else {
#pragma unroll
    for (int i = 0; i < 4; ++i) {
      ta[ly + i * 8][lx] = W[(I * 32 + ly + i * 8) * NN + J * 32 + lx];
      tb[ly + i * 8][lx] = W[(J * 32 + ly + i * 8) * NN + I * 32 + lx];
    }
    __syncthreads();
#pragma unroll
    for (int i = 0; i < 4; ++i) {
      const int idxA = (J * 32 + ly + i * 8) * NN + I * 32 + lx;
      const float va = ta[lx][ly + i * 8];
      const uint32_t bitsA = __float_as_uint(va);
      W[idxA] = va;
      WtBf[idxA] = (uint16_t)(bitsA >> 16);
      bad |= (bitsA & 0xFFFFu);

      const int idxB = (I * 32 + ly + i * 8) * NN + J * 32 + lx;
      const float vb = tb[lx][ly + i * 8];
      const uint32_t bitsB = __float_as_uint(vb);
      W[idxB] = vb;
      WtBf[idxB] = (uint16_t)(bitsB >> 16);
      bad |= (bitsB & 0xFFFFu);
    }
  }
  const unsigned long long bm = __ballot(bad != 0);
  if ((threadIdx.x & 63) == 0 && bm) atomicOr(dirty, 1u);
}

// ---------------------------------------------------------------------------
// Kernel 1a (primary): per-HALF-sample LIF. 256 blocks x 512 threads; block
// bb handles sample b = bb&127, neuron half h = bb>>7. Partner bb^128.
// Per step: local ballot (8 u64 chunks), tagged-cell fenceless exchange,
// full 1024-entry active list rebuilt locally, then the wave-private
// batched-staging gather (8 rows per gload_lds16, dbuf, no barriers).
// ---------------------------------------------------------------------------
__global__ __launch_bounds__(512) void lif_half(
    const void* __restrict__ tx_raw, const float* __restrict__ bias,
    const float* __restrict__ WtF32, const uint16_t* __restrict__ WtBf,
    const uint32_t* __restrict__ dirty,
    unsigned long long* __restrict__ gmask, float* __restrict__ out) {
  const int bb = blockIdx.x;
  const int b = bb & 127;         // sample
  const int h = bb >> 7;          // neuron half
  const int pp = bb ^ 128;        // partner block (other half)
  const int tid = threadIdx.x;    // 0..511
  const int lane = tid & 63;
  const int wv = tid >> 6;        // 0..7
  const int n = (h << 9) + tid;   // global neuron index == recurrent index k

  __shared__ uint16_t wbuf[8][2][512] __attribute__((aligned(16)));  // 16KB
  __shared__ uint16_t lst[NN] __attribute__((aligned(16)));
  __shared__ unsigned long long smask[16];  // chunk j covers k in [j*64,(j+1)*64)
  __shared__ int sprobe;

  // ---- runtime tx-storage probe (bf16-packed vs f32), as verified in R9 ----
  if (tid == 0) sprobe = 0;
  __syncthreads();
  {
    const uint32_t* txw = (const uint32_t*)tx_raw;
    int local = 0;
#pragma unroll
    for (int i = 0; i < 2; ++i) {
      const uint32_t f = (txw[tid * 2 + i] >> 7) & 0xFFu;
      local += (f >= 0x74u && f < 0x81u) ? 1 : 0;
    }
    atomicAdd(&sprobe, local);
  }
  __syncthreads();
  const bool tx_is_bf16 = (sprobe > 512);    // of 1024 sampled words
  const bool w_bf = (*dirty == 0u);          // bf16 repack lossless?

  const uint16_t* __restrict__ txh = (const uint16_t*)tx_raw;
  const float* __restrict__ txf = (const float*)tx_raw;
  const float bz = bias[n];

  const char* __restrict__ wbase = (const char*)WtBf;
  const float* __restrict__ rowF = WtF32 + n;
  // per-lane source byte offset within a staged row batch:
  //   wave slice at byte wv*128 of the half-row (h*1024), lane-group row
  //   (lane>>3), within-slice bytes (lane&7)*16
  const size_t lbyte = (size_t)(h << 10) + (size_t)(wv << 7) +
                       (size_t)((lane & 7) << 4);
  const int lrow = lane >> 3;  // which of the 8 batch rows this lane stages

  float v = 0.0f;   // membrane (REST = 0)
  int y = 0;        // previous spike

  // f32 fallback (cold path): unpadded bounds [s, e), 8-wide structure.
  auto gF = [&](int s, int e) -> float {
    float acc = 0.0f;
    int i = s;
    for (; i + 8 <= e; i += 8) {
      float w[8];
#pragma unroll
      for (int u = 0; u < 8; ++u) {
        const int k = __builtin_amdgcn_readfirstlane((int)lst[i + u]);
        w[u] = rowF[k << 10];
      }
#pragma unroll
      for (int u = 0; u < 8; ++u) acc += w[u];
    }
    for (; i < e; ++i) {
      const int k = __builtin_amdgcn_readfirstlane((int)lst[i]);
      acc += rowF[k << 10];
    }
    return acc;
  };

  for (int t = 0; t < TT; ++t) {
    const int sl = t & 3;  // mod-4 slot
    // ---- local ballot + publish tagged cells (relaxed, fenceless) ----
    const unsigned long long m = __ballot(y);
    if (lane == 0) smask[h * 8 + wv] = m;
    if (lane < 2) {
      const uint32_t word = (lane == 0) ? (uint32_t)m : (uint32_t)(m >> 32);
      const unsigned long long cell =
          ((unsigned long long)(t + 1) << 32) | (unsigned long long)word;
      __hip_atomic_store(&gmask[((size_t)bb * 4 + sl) * 16 + wv * 2 + lane],
                         cell, __ATOMIC_RELAXED, __HIP_MEMORY_SCOPE_AGENT);
    }

    // issue tx load early; consumed after the gather
    const int off = (t * BB + b) * NN + n;
    float xx;
    if (tx_is_bf16)
      xx = bfbits2f((uint32_t)__builtin_nontemporal_load(&txh[off]));
    else
      xx = __builtin_nontemporal_load(&txf[off]);

    __syncthreads();  // SYNC_A: own smask half visible; prior step fully done
    if (tid < 16) {
      // spin on partner's tagged cell; tag==t+1 guarantees payload is the
      // step-t word (single-cell atomicity; no fences required)
      const size_t ci = ((size_t)pp * 4 + sl) * 16 + tid;
      unsigned long long cell;
      while (((cell = __hip_atomic_load(&gmask[ci], __ATOMIC_RELAXED,
                                        __HIP_MEMORY_SCOPE_AGENT)) >>
              32) != (unsigned long long)(t + 1)) {
        __builtin_amdgcn_s_sleep(1);
      }
      ((uint32_t*)smask)[(1 - h) * 16 + tid] = (uint32_t)cell;
    }
    __syncthreads();  // SYNC_B: all 16 mask chunks in LDS

    // ---- per-thread counts/prefixes from the 16 mask chunks ----
    unsigned long long mk[16];
    int cnt[16];
#pragma unroll
    for (int i = 0; i < 16; ++i) {
      mk[i] = smask[i];
      cnt[i] = __popcll(mk[i]);
    }
    int pref[16];
    {
      int s = 0;
#pragma unroll
      for (int j = 0; j < 6; ++j) { pref[j] = s; s += cnt[j]; }
    }
    {
      int s = 384;
#pragma unroll
      for (int j = 6; j < 12; ++j) { pref[j] = s; s += cnt[j]; }
    }
    {
      int s = 768;
#pragma unroll
      for (int j = 12; j < 16; ++j) { pref[j] = s; s += cnt[j]; }
    }
    const int c0 = pref[5] + cnt[5];          // panel 0 count (k < 384)
    const int c1 = pref[11] + cnt[11] - 384;  // panel 1 count
    const int c2 = pref[15] + cnt[15] - 768;  // panel 2 count

    // ---- build full active list: wave wv materializes chunks 2wv, 2wv+1 ----
#pragma unroll
    for (int jj = 0; jj < 2; ++jj) {
      const int j = wv * 2 + jj;
      const unsigned long long bits = mk[j];
      if ((bits >> lane) & 1ull) {
        const int below = __builtin_amdgcn_mbcnt_hi(
            (uint32_t)(bits >> 32),
            __builtin_amdgcn_mbcnt_lo((uint32_t)bits, 0));
        lst[pref[j] + below] = (uint16_t)(j * 64 + lane);
      }
    }
    // sentinel padding to x8 per panel (k=NN -> zeroed row, +0.0f exact)
    if (tid < 24) {
      const int p = tid >> 3, jn = tid & 7;
      const int c = (p == 0) ? c0 : ((p == 1) ? c1 : c2);
      if (c + jn < ((c + 7) & ~7)) lst[p * 384 + c + jn] = (uint16_t)NN;
    }
    __syncthreads();  // SYNC_C: lst complete

    // ---- recurrent term: (P0 + P1) + P2, sequential k within panels ----
    float P0 = 0.0f, P1 = 0.0f, P2 = 0.0f;
    if (w_bf) {
      const int n0c = (c0 + 7) >> 3;
      const int n1c = (c1 + 7) >> 3;
      const int n2c = (c2 + 7) >> 3;
      const int nct = n0c + n1c + n2c;

      uint16_t* const wb0 = &wbuf[wv][0][0];
      uint16_t* const wb1 = &wbuf[wv][1][0];

      auto pbase = [&](int c) -> int {
        if (c < n0c) return c * 8;
        if (c < n0c + n1c) return 384 + (c - n0c) * 8;
        return 768 + (c - n0c - n1c) * 8;
      };
      // stage batch c (8 rows x this wave's 128B slice) with ONE gload:
      // lane j sources row lst[pb + (j>>3)], bytes (j&7)*16; linear LDS
      // dest lane*16 lands row-major [8][128B] in dst.
      auto stage = [&](int c, uint16_t* dst) {
        const int k = (int)lst[pbase(c) + lrow];  // per-lane LDS read
        gload_lds16(wbase + ((size_t)k << 11) + lbyte, dst);
      };

      if (nct > 0) {
        stage(0, wb0);
        if (nct > 1) stage(1, wb1);
        for (int c = 0; c < nct; ++c) {
          uint16_t* const buf = (c & 1) ? wb1 : wb0;
          // batch c staged (next batch's gload may stay in flight)
          if (c + 1 < nct)
            asm volatile("s_waitcnt vmcnt(1)" ::: "memory");
          else
            asm volatile("s_waitcnt vmcnt(0)" ::: "memory");
          // read this thread's column for the 8 rows (2-way alias = free)
          uint16_t vals[8];
#pragma unroll
          for (int r = 0; r < 8; ++r) vals[r] = buf[r * 64 + lane];
          // ds_reads must land before this buffer is re-staged
          asm volatile("s_waitcnt lgkmcnt(0)" ::: "memory");
          if (c + 2 < nct) stage(c + 2, buf);
          // ordered adds: ascending k, ONE accumulator per panel (exact)
          if (c < n0c) {
#pragma unroll
            for (int r = 0; r < 8; ++r) P0 += bfbits2f((uint32_t)vals[r]);
          } else if (c < n0c + n1c) {
#pragma unroll
            for (int r = 0; r < 8; ++r) P1 += bfbits2f((uint32_t)vals[r]);
          } else {
#pragma unroll
            for (int r = 0; r < 8; ++r) P2 += bfbits2f((uint32_t)vals[r]);
          }
        }
      }
    } else {
      P0 = gF(0, c0);
      P1 = gF(384, 384 + c1);
      P2 = gF(768, 768 + c2);
    }
    const float a = (P0 + P1) + P2;

    // ---- LIF update, reference op order, f32 ----
    const float xv = (xx + a) + bz;
    v = (y ? 0.0f : 0.5f * v) + xv;
    y = (v > 0.5f);

    __builtin_nontemporal_store(y ? 1.0f : 0.0f, &out[off]);
    // No end-of-step barrier needed: smask/lst(t+1) writes happen after
    // SYNC_A/B(t+1), which every wave reaches only after finishing its
    // gather(t) (per-wave program order); wave-private wbuf has no
    // cross-wave hazard at all.
  }
}

// ---------------------------------------------------------------------------
// Kernel 1b (fallback, R10-verified): per-sample LIF, 128 blocks x 1024 thr.
// Used only if ws_size cannot hold the mask exchange buffers.
// ---------------------------------------------------------------------------
__global__ __launch_bounds__(1024) void lif_persample(
    const void* __restrict__ tx_raw, const float* __restrict__ bias,
    const float* __restrict__ WtF32, const uint16_t* __restrict__ WtBf,
    const uint32_t* __restrict__ dirty, float* __restrict__ out) {
  const int b = blockIdx.x;
  const int tid = threadIdx.x;
  const int lane = tid & 63;
  const int wv = tid >> 6;

  __shared__ uint16_t lst[NN] __attribute__((aligned(16)));
  __shared__ int wcnt[16];
  __shared__ int sprobe;

  if (tid == 0) sprobe = 0;
  __syncthreads();
  {
    const uint32_t* txw = (const uint32_t*)tx_raw;
    int local = 0;
#pragma unroll
    for (int i = 0; i < 2; ++i) {
      const uint32_t f = (txw[tid * 2 + i] >> 7) & 0xFFu;
      local += (f >= 0x74u && f < 0x81u) ? 1 : 0;
    }
    atomicAdd(&sprobe, local);
  }
  __syncthreads();
  const bool tx_is_bf16 = (sprobe > 1024);
  const bool w_bf = (*dirty == 0u);

  const uint16_t* __restrict__ txh = (const uint16_t*)tx_raw;
  const float* __restrict__ txf = (const float*)tx_raw;
  const float bz = bias[tid];

  const int pidx = (wv < 6) ? 0 : ((wv < 12) ? 1 : 2);
  const int pw0 = (pidx == 0) ? 0 : ((pidx == 1) ? 6 : 12);

  const uint16_t* __restrict__ rowB = WtBf + tid;
  const float* __restrict__ rowF = WtF32 + tid;

  float v = 0.0f;
  int y = 0;

  auto gB = [&](int pbase, int cnt) -> float {
    float acc = 0.0f;
    for (int i = 0; i < cnt; i += 32) {
      const ushort8* lp = (const ushort8*)(lst + pbase + i);
      const ushort8 a0 = lp[0];
      const ushort8 a1 = lp[1];
      const ushort8 a2 = lp[2];
      const ushort8 a3 = lp[3];
      float wbuf[32];
#pragma unroll
      for (int u = 0; u < 8; ++u) {
        const int k = __builtin_amdgcn_readfirstlane((int)a0[u]);
        wbuf[u] = bfbits2f((uint32_t)rowB[k << 10]);
      }
#pragma unroll
      for (int u = 0; u < 8; ++u) {
        const int k = __builtin_amdgcn_readfirstlane((int)a1[u]);
        wbuf[8 + u] = bfbits2f((uint32_t)rowB[k << 10]);
      }
#pragma unroll
      for (int u = 0; u < 8; ++u) {
        const int k = __builtin_amdgcn_readfirstlane((int)a2[u]);
        wbuf[16 + u] = bfbits2f((uint32_t)rowB[k << 10]);
      }
#pragma unroll
      for (int u = 0; u < 8; ++u) {
        const int k = __builtin_amdgcn_readfirstlane((int)a3[u]);
        wbuf[24 + u] = bfbits2f((uint32_t)rowB[k << 10]);
      }
#pragma unroll
      for (int u = 0; u < 32; ++u) acc += wbuf[u];
    }
    return acc;
  };

  auto gF = [&](int s, int e) -> float {
    float acc = 0.0f;
    int i = s;
    for (; i + 8 <= e; i += 8) {
      float w[8];
#pragma unroll
      for (int u = 0; u < 8; ++u) {
        const int k = __builtin_amdgcn_readfirstlane((int)lst[i + u]);
        w[u] = rowF[k << 10];
      }
#pragma unroll
      for (int u = 0; u < 8; ++u) acc += w[u];
    }
    for (; i < e; ++i) {
      const int k = __builtin_amdgcn_readfirstlane((int)lst[i]);
      acc += rowF[k << 10];
    }
    return acc;
  };

  for (int t = 0; t < TT; ++t) {
    const unsigned long long m = __ballot(y);
    if (lane == 0) wcnt[wv] = __popcll(m);
    __syncthreads();
    int base = 0, c0 = 0, c1 = 0, c2 = 0;
#pragma unroll
    for (int w = 0; w < 16; ++w) {
      const int c = wcnt[w];
      c0 += (w < 6) ? c : 0;
      c1 += (w >= 6 && w < 12) ? c : 0;
      c2 += (w >= 12) ? c : 0;
      base += (w >= pw0 && w < wv) ? c : 0;
    }
    if (y) {
      const int below = __builtin_amdgcn_mbcnt_hi(
          (uint32_t)(m >> 32), __builtin_amdgcn_mbcnt_lo((uint32_t)m, 0));
      lst[pidx * 384 + base + below] = (uint16_t)tid;
    }
    if (tid < 96) {
      const int p = tid >> 5, jn = tid & 31;
      const int c = (p == 0) ? c0 : ((p == 1) ? c1 : c2);
      if (c + jn < ((c + 31) & ~31)) lst[p * 384 + c + jn] = (uint16_t)NN;
    }
    __syncthreads();

    float P0, P1, P2;
    if (w_bf) {
      P0 = gB(0, (c0 + 31) & ~31);
      P1 = gB(384, (c1 + 31) & ~31);
      P2 = gB(768, (c2 + 31) & ~31);
    } else {
      P0 = gF(0, c0);
      P1 = gF(384, 384 + c1);
      P2 = gF(768, 768 + c2);
    }
    const float a = (P0 + P1) + P2;

    const int off = (t * BB + b) * NN + tid;
    const float xx = tx_is_bf16
        ? bfbits2f((uint32_t)__builtin_nontemporal_load(&txh[off]))
        : __builtin_nontemporal_load(&txf[off]);
    const float xv = (xx + a) + bz;
    v = (y ? 0.0f : 0.5f * v) + xv;
    y = (v > 0.5f);

    __builtin_nontemporal_store(y ? 1.0f : 0.0f, &out[off]);
  }
}

extern "C" void kernel_launch(void* const* d_in, const int* in_sizes, int n_in,
                              void* d_out, int out_size, void* d_ws, size_t ws_size,
                              hipStream_t stream) {
  // Inputs by element count: tx = 128*128*1024 (bf16-packed),
  // W = 1024*1024 (f32, bf16-valued), b = 1024 (f32).
  const void* tx = nullptr;
  float* W = nullptr;
  const float* bs = nullptr;
  for (int i = 0; i < n_in; ++i) {
    if (in_sizes[i] == TT * BB * NN) tx = d_in[i];
    else if (in_sizes[i] == NN * NN) W = (float*)d_in[i];
    else if (in_sizes[i] == NN) bs = (const float*)d_in[i];
  }
  float* out = (float*)d_out;                     // [T, B, N] f32 spikes

  // Workspace layout:
  //   [0, 2MB)                bf16 W^T (1024 rows)
  //   [2MB, 2MB+2KB)          zero row (sentinel k=1024)
  //   @2MB+2048               dirty flag (u32)
  //   @2MB+4096               gmask: u64[256 blocks][4 slots][16 cells] = 128KB
  const size_t MB2 = 2u * 1024u * 1024u;
  uint16_t* WtBf = (uint16_t*)d_ws;
  uint16_t* zrow = WtBf + NN * NN;                // row index 1024
  uint32_t* dirty = (uint32_t*)((char*)d_ws + MB2 + 2048u);
  unsigned long long* gmask =
      (unsigned long long*)((char*)d_ws + MB2 + 4096u);
  const size_t GMASK_BYTES = 256u * 4u * 16u * 8u;  // 131072
  const size_t need = MB2 + 4096u + GMASK_BYTES;

  // ws is poisoned 0xAA each launch — clear dirty flag, sentinel row, cells.
  hipMemsetAsync(dirty, 0, sizeof(uint32_t), stream);
  hipMemsetAsync(zrow, 0, NN * sizeof(uint16_t), stream);

  w_transpose_repack<<<dim3(528), dim3(256), 0, stream>>>(W, WtBf, dirty);

  if (ws_size >= need) {
    hipMemsetAsync(gmask, 0, GMASK_BYTES, stream);
    lif_half<<<dim3(256), dim3(512), 0, stream>>>(tx, bs, W, WtBf, dirty,
                                                  gmask, out);
  } else {
    lif_persample<<<dim3(BB), dim3(1024), 0, stream>>>(tx, bs, W, WtBf, dirty,
                                                       out);
  }
}